// Round 6
// baseline (144.758 us; speedup 1.0000x reference)
//
#include <hip/hip_runtime.h>

#define B_    4
#define NPTS  8192          // N == M == 8192
#define NJ    64            // j-chunks per direction
#define JC    (NPTS / NJ)   // 128 dst points per chunk
#define JP    (JC / 2)      // 64 dst pairs per chunk
#define PT    16            // src points per thread (halves LDS traffic vs R5)
#define BLK   256
#define ITILE (BLK * PT)    // 4096 src points per block
#define TOT   (B_ * NPTS)   // 32768
#define NBLK  ((NPTS / ITILE) * NJ * 2 * B_)   // (2)*(64)*(8) = 1024

// ws: slots uint32[2*TOT] = 256 KiB @ 0   (memset 0xFF each launch)
//     cnt   uint32[1]            @ 256K   (memset 0    each launch)
// Monotone map: u = bits ^ ((bits>>31) | 0x80000000); uint cmp == float cmp.

__device__ __forceinline__ float slot_decode(unsigned u) {
  const int bi = (u & 0x80000000u) ? (int)(u ^ 0x80000000u) : (int)~u;
  return __int_as_float(bi);
}

// Fully fused: transform + stage + min + atomicMin + last-block reduction.
// grid (NPTS/ITILE, NJ, 2*B_) = (2,64,8) = 1024 blocks -> 4 blocks/CU,
// 16 waves/CU. Per-eval cost at the scalar-FMA floor: 3 fma + 0.5 min3.
// PT=16 keeps ds_read_b128 at ~43% of VALU-critical time (R5's PT=8 had
// the LDS pipe at 86% -> lgkmcnt stalls were the 44us-vs-36us gap).
__global__ __launch_bounds__(BLK, 4) void chamfer_kernel(
    const float* __restrict__ pred, const float* __restrict__ gt,
    unsigned* __restrict__ slots, unsigned* __restrict__ cnt,
    float* __restrict__ out) {
  __shared__ float4 lds[JC];   // per dst point: (-2x, -2y, -2z, ||g||^2)
  __shared__ float red[BLK];
  __shared__ unsigned s_order;

  const int zb  = blockIdx.z;
  const int dir = zb >> 2;          // 0: pred->gt, 1: gt->pred
  const int b   = zb & 3;
  const float* src = dir ? gt   : pred;
  const float* dst = dir ? pred : gt;

  const int tid   = threadIdx.x;
  const int jbase = blockIdx.y * JC;
  const int ibase = blockIdx.x * ITILE;

  // Stage + transform one dst point per thread (JC == 128: waves 0-1).
  if (tid < JC) {
    const float* g = dst + ((size_t)b * NPTS + jbase + tid) * 3;
    const float x = g[0], y = g[1], z = g[2];
    lds[tid] = make_float4(-2.f * x, -2.f * y, -2.f * z,
                           fmaf(x, x, fmaf(y, y, z * z)));
  }

  float px[PT], py[PT], pz[PT], m[PT];
#pragma unroll
  for (int p = 0; p < PT; ++p) {
    const int i = ibase + p * BLK + tid;
    const float* s = src + ((size_t)b * NPTS + i) * 3;
    px[p] = s[0]; py[p] = s[1]; pz[p] = s[2];
    m[p] = 1e30f;
  }
  __syncthreads();

#pragma unroll 2
  for (int jp = 0; jp < JP; ++jp) {
    const float4 g0 = lds[2 * jp + 0];   // wave-uniform -> broadcast, 0 conflicts
    const float4 g1 = lds[2 * jp + 1];
#pragma unroll
    for (int p = 0; p < PT; ++p) {
      const float t0 = fmaf(pz[p], g0.z, fmaf(py[p], g0.y, fmaf(px[p], g0.x, g0.w)));
      const float t1 = fmaf(pz[p], g1.z, fmaf(py[p], g1.y, fmaf(px[p], g1.x, g1.w)));
      asm("v_min3_f32 %0, %1, %2, %3"
          : "=v"(m[p]) : "v"(t0), "v"(t1), "v"(m[p]));
    }
  }

  // dist = ||p||^2 + chunk-min; monotone uint map; coalesced atomicMin.
#pragma unroll
  for (int p = 0; p < PT; ++p) {
    const int i = ibase + p * BLK + tid;
    const float d = fmaf(px[p], px[p], fmaf(py[p], py[p], pz[p] * pz[p])) + m[p];
    const int   bi = __float_as_int(d);
    const unsigned u = (unsigned)bi ^ (unsigned)((bi >> 31) | 0x80000000);
    atomicMin(&slots[(size_t)(dir * B_ + b) * NPTS + i], u);
  }

  // ---- last-block-done final reduction (replaces pass2) ----
  __threadfence();                  // release our atomics (device scope)
  __syncthreads();
  if (tid == 0) s_order = atomicAdd(cnt, 1u);
  __syncthreads();
  if (s_order != NBLK - 1) return;  // uniform per block
  __threadfence();                  // acquire: invalidate vL1 before reading slots

  float s = 0.f;
  const uint4* s4 = (const uint4*)slots;      // 2*TOT/4 = 16384 uint4
#pragma unroll 4
  for (int k = 0; k < (2 * TOT / 4) / BLK; ++k) {   // 64 coalesced uint4 loads
    const uint4 v = s4[tid + k * BLK];
    s += slot_decode(v.x) + slot_decode(v.y) +
         slot_decode(v.z) + slot_decode(v.w);
  }
  red[tid] = s;
  __syncthreads();
  for (int st = 128; st > 0; st >>= 1) {
    if (tid < st) red[tid] += red[tid + st];
    __syncthreads();
  }
  if (tid == 0) out[0] = red[0] * (1.0f / TOT);   // single writer, no memset
}

extern "C" void kernel_launch(void* const* d_in, const int* in_sizes, int n_in,
                              void* d_out, int out_size, void* d_ws, size_t ws_size,
                              hipStream_t stream) {
  const float* pred = (const float*)d_in[0];
  const float* gt   = (const float*)d_in[1];
  unsigned* slots = (unsigned*)d_ws;
  unsigned* cnt   = (unsigned*)((char*)d_ws + (size_t)2 * TOT * sizeof(unsigned));
  float* out = (float*)d_out;

  hipMemsetAsync(slots, 0xFF, (size_t)2 * TOT * sizeof(unsigned), stream);
  hipMemsetAsync(cnt, 0, sizeof(unsigned), stream);

  dim3 g(NPTS / ITILE, NJ, 2 * B_);   // (2, 64, 8) = 1024 blocks
  chamfer_kernel<<<g, BLK, 0, stream>>>(pred, gt, slots, cnt, out);
}

// Round 9
// 98.728 us; speedup vs baseline: 1.4662x; 1.4662x over previous
//
#include <hip/hip_runtime.h>

typedef short short8 __attribute__((ext_vector_type(8)));
typedef float floatx4 __attribute__((ext_vector_type(4)));

#define B_    4
#define NPTS  8192          // N == M == 8192
#define IS    16            // i-splits (512 src per block)
#define JS    16            // j-splits (512 dst per block)
#define ITB   512
#define JTB   512
#define NT    8             // i-tiles per wave (16 i each -> 128 i/wave)
#define NJT   32            // j-tiles per block
#define TOT   (B_ * NPTS)   // 32768

// LDS offsets in short8 units (typed array => 16B-aligned, no raw casts).
// A0/A1: dst k0..7 / k8..15.  B0/B1: src k0..7 / k8..15.  Z: zero block
// read by quads 2,3 (k16..31 true zeros -> exact sum over k0..15 only).
#define A0OFF 0
#define A1OFF 516           // +4 pad blocks: bank-shift 16 vs A0
#define B0OFF 1032
#define B1OFF 1548
#define ZOFF  2064
#define LDS8N 2065          // 33,040 B -> 4 blocks/CU

// ws: slots uint32[2*TOT] = 256 KiB, memset 0xFF. Monotone float->uint map.

__device__ __forceinline__ unsigned short bf16h(float v) {
  unsigned u = __float_as_uint(v);
  return (unsigned short)((u + 0x7FFFu + ((u >> 16) & 1u)) >> 16);   // RNE
}
__device__ __forceinline__ void bf16split(float v, unsigned short& h, unsigned short& l) {
  h = bf16h(v);
  l = bf16h(v - __uint_as_float((unsigned)h << 16));
}

// K-slot scheme (k0..15 real, k16..31 zero):
//   A (dst j): k0..7  [axh axh axl axl  ayh ayh ayl ayl]      a = -2g
//              k8..15 [azh azh azl azl  wh  wl  1   1 ]       w = ||g||^2
//   B (src i): k0..7  [pxh pxl pxh pxl  pyh pyl pyh pyl]
//              k8..15 [pzh pzl pzh pzl  1   1   qh  ql]       q = ||p||^2
// Sum_k A[j][k]B[k][i] = -2<g,p> + ||g||^2 + ||p||^2 = squared distance.
// (hi*hi etc products are exact in fp32: 8b x 8b mantissas; split err ~2^-17)
__device__ __forceinline__ void pack_dst(const float* g, short8& s0, short8& s1) {
  const float x = g[0], y = g[1], z = g[2];
  const float w = fmaf(x, x, fmaf(y, y, z * z));
  unsigned short xh, xl, yh, yl, zh, zl, wh, wl;
  bf16split(-2.f * x, xh, xl); bf16split(-2.f * y, yh, yl);
  bf16split(-2.f * z, zh, zl); bf16split(w, wh, wl);
  s0 = (short8){(short)xh,(short)xh,(short)xl,(short)xl,
                (short)yh,(short)yh,(short)yl,(short)yl};
  s1 = (short8){(short)zh,(short)zh,(short)zl,(short)zl,
                (short)wh,(short)wl,(short)0x3F80,(short)0x3F80};
}
__device__ __forceinline__ void pack_src(const float* p, short8& s0, short8& s1) {
  const float x = p[0], y = p[1], z = p[2];
  const float qq = fmaf(x, x, fmaf(y, y, z * z));
  unsigned short xh, xl, yh, yl, zh, zl, qh, ql;
  bf16split(x, xh, xl); bf16split(y, yh, yl);
  bf16split(z, zh, zl); bf16split(qq, qh, ql);
  s0 = (short8){(short)xh,(short)xl,(short)xh,(short)xl,
                (short)yh,(short)yl,(short)yh,(short)yl};
  s1 = (short8){(short)zh,(short)zl,(short)zh,(short)zl,
                (short)0x3F80,(short)0x3F80,(short)qh,(short)ql};
}

// grid (IS, JS, 2*B_) = (16,16,8) = 2048 blocks, 256 thr (4 waves).
// Block: 512 i x 512 j. Wave w: i in [w*128, w*128+128), all 512 j.
// All LDS reads are 16B-aligned typed accesses at valid addresses for every
// lane (quads 2,3 -> Z block): nothing for the compiler to speculate wrong.
__global__ __launch_bounds__(256, 4) void mfma_pass_kernel(
    const float* __restrict__ pred, const float* __restrict__ gt,
    unsigned* __restrict__ slots) {
  __shared__ short8 lds8[LDS8N];

  const int zb  = blockIdx.z;
  const int dir = zb >> 2;
  const int b   = zb & 3;
  const float* src = dir ? gt   : pred;   // i-cloud (min FOR these)
  const float* dst = dir ? pred : gt;     // j-cloud (min OVER these)

  const int tid   = threadIdx.x;
  const int lane  = tid & 63;
  const int w     = tid >> 6;
  const int jbase = blockIdx.y * JTB;
  const int ibase = blockIdx.x * ITB;

  if (tid == 0) lds8[ZOFF] = (short8)0;

  // Stage both tiles: 512 dst + 512 src points, 2 each per thread.
#pragma unroll
  for (int r = 0; r < 2; ++r) {
    const int pt = tid + r * 256;
    short8 s0, s1;
    pack_dst(dst + ((size_t)b * NPTS + jbase + pt) * 3, s0, s1);
    lds8[A0OFF + pt] = s0;
    lds8[A1OFF + pt] = s1;
    pack_src(src + ((size_t)b * NPTS + ibase + pt) * 3, s0, s1);
    lds8[B0OFF + pt] = s0;
    lds8[B1OFF + pt] = s1;
  }
  __syncthreads();

  const int  q  = lane >> 4;     // quad: holds k = q*8..q*8+7 of A and B
  const int  n  = lane & 15;     // point index within tile (A: j, B: i)
  const bool kq = (q < 2);       // quads 0,1 carry real k; 2,3 carry zeros

  // B fragments: one-time loads (valid address for every lane).
  short8 bf[NT];
  float  m[NT];
  const int bseg = kq ? (q ? B1OFF : B0OFF) : ZOFF;
#pragma unroll
  for (int t = 0; t < NT; ++t) {
    bf[t] = lds8[bseg + (kq ? (w * 128 + t * 16 + n) : 0)];
    m[t] = 1e30f;
  }

  const int aseg  = kq ? (q ? A1OFF : A0OFF) : ZOFF;
  const int abase = aseg + (kq ? n : 0);
  const int astep = kq ? 16 : 0;   // quads 2,3 stay pinned on the zero block

  const floatx4 zero4 = {0.f, 0.f, 0.f, 0.f};
  for (int jt = 0; jt < NJT; ++jt) {
    const short8 af = lds8[abase + jt * astep];
#pragma unroll
    for (int t = 0; t < NT; ++t) {
      // D[j][i]: lane holds col i=n, rows j = 4q..4q+3 (C/D layout m89/m91).
      floatx4 d = __builtin_amdgcn_mfma_f32_16x16x32_bf16(af, bf[t], zero4, 0, 0, 0);
      m[t] = fminf(m[t], fminf(fminf(d[0], d[1]), fminf(d[2], d[3])));
    }
  }

  // Cross-quad min (lanes n, n+16, n+32, n+48 hold rows of the same i=n),
  // then ONE atomicMin per (i, block).
#pragma unroll
  for (int t = 0; t < NT; ++t) {
    float v = m[t];
    v = fminf(v, __shfl_xor(v, 16));
    v = fminf(v, __shfl_xor(v, 32));
    if (lane < 16) {
      const int gi = ibase + w * 128 + t * 16 + lane;
      const int bi = __float_as_int(v);
      const unsigned u = (unsigned)bi ^ (unsigned)((bi >> 31) | 0x80000000);
      atomicMin(&slots[(size_t)(dir * B_ + b) * NPTS + gi], u);
    }
  }
}

// Sweep 2*TOT slots, decode, reduce, one atomic per block.  (R5-proven)
__global__ __launch_bounds__(256) void pass2_kernel(
    const unsigned* __restrict__ slots, float* __restrict__ out) {
  const int gid = blockIdx.x * 256 + threadIdx.x;   // 8192 threads
  float s = 0.f;
#pragma unroll
  for (int k = 0; k < 8; ++k) {
    const unsigned u = slots[gid + k * 8192];
    const int bi = (u & 0x80000000u) ? (int)(u ^ 0x80000000u) : (int)~u;
    s += __int_as_float(bi);
  }
  __shared__ float red[256];
  const int tid = threadIdx.x;
  red[tid] = s;
  __syncthreads();
  for (int st = 128; st > 0; st >>= 1) {
    if (tid < st) red[tid] += red[tid + st];
    __syncthreads();
  }
  if (tid == 0) atomicAdd(out, red[0] * (1.0f / TOT));
}

extern "C" void kernel_launch(void* const* d_in, const int* in_sizes, int n_in,
                              void* d_out, int out_size, void* d_ws, size_t ws_size,
                              hipStream_t stream) {
  const float* pred = (const float*)d_in[0];
  const float* gt   = (const float*)d_in[1];
  unsigned* slots = (unsigned*)d_ws;
  float* out = (float*)d_out;

  hipMemsetAsync(slots, 0xFF, (size_t)2 * TOT * sizeof(unsigned), stream);
  hipMemsetAsync(out, 0, out_size * sizeof(float), stream);

  dim3 g(IS, JS, 2 * B_);   // 2048 blocks
  mfma_pass_kernel<<<g, 256, 0, stream>>>(pred, gt, slots);

  pass2_kernel<<<(2 * TOT) / (256 * 8), 256, 0, stream>>>(slots, out);
}